// Round 1
// baseline (33467.969 us; speedup 1.0000x reference)
//
#include <hip/hip_runtime.h>
#include <math.h>

#define kB 2
#define kH 256
#define kW 256
#define kHW 65536
#define kNSPIX 256
#define kC 20
#define kNITER 10

// ---------------------------------------------------------------------------
// Conv 3x3 SAME, fp32 direct (implicit GEMM). Tile: 64 cout x 64 px, BK=8 cin.
// 256 threads; each thread computes 4 cout x 4 px.
// ---------------------------------------------------------------------------
__global__ __launch_bounds__(256) void conv3x3(
    const float* __restrict__ in, const float* __restrict__ wgt,
    float* __restrict__ out, int Cin, int Cout, long in_bstride, long out_bstride)
{
    __shared__ float s_in[8][3][66];   // [ci][row][x0-1 .. x0+64]
    __shared__ float s_w[64][73];      // [co][ci*9+tap], stride 73 breaks bank conflicts

    const int tid   = threadIdx.x;
    const int tileX = blockIdx.x & 3;        // W/64 = 4 tiles
    const int yRow  = blockIdx.x >> 2;       // 0..255
    const int co0   = blockIdx.y * 64;
    const int b     = blockIdx.z;
    const int x0    = tileX * 64;

    const int px_base = (tid & 15) * 4;
    const int co_base = (tid >> 4) * 4;

    float acc[4][4];
    #pragma unroll
    for (int i = 0; i < 4; ++i)
        #pragma unroll
        for (int j = 0; j < 4; ++j) acc[i][j] = 0.f;

    const float* in_b = in + (long)b * in_bstride;

    for (int ci0 = 0; ci0 < Cin; ci0 += 8) {
        // ---- stage input tile: 8 ci x 3 rows x 66 px ----
        for (int e = tid; e < 8 * 3 * 66; e += 256) {
            int ci  = e / 198;
            int rem = e - ci * 198;
            int rr  = rem / 66;
            int xx  = rem - rr * 66;
            int y   = yRow + rr - 1;
            int x   = x0 + xx - 1;
            int cig = ci0 + ci;
            float v = 0.f;
            if (cig < Cin && (unsigned)y < kH && (unsigned)x < kW)
                v = in_b[(long)cig * kHW + y * kW + x];
            s_in[ci][rr][xx] = v;
        }
        // ---- stage weights: 64 co x 8 ci x 9 taps ----
        for (int e = tid; e < 64 * 72; e += 256) {
            int co  = e / 72;
            int rem = e - co * 72;          // ci*9 + tap
            int ci  = rem / 9;
            int cog = co0 + co, cig = ci0 + ci;
            float v = 0.f;
            if (cog < Cout && cig < Cin)
                v = wgt[((long)cog * Cin + cig) * 9 + (rem - ci * 9)];
            s_w[co][rem] = v;
        }
        __syncthreads();

        #pragma unroll
        for (int ci = 0; ci < 8; ++ci) {
            float wv[4][9];
            #pragma unroll
            for (int i = 0; i < 4; ++i)
                #pragma unroll
                for (int t = 0; t < 9; ++t)
                    wv[i][t] = s_w[co_base + i][ci * 9 + t];
            #pragma unroll
            for (int rr = 0; rr < 3; ++rr) {
                float xv[6];
                #pragma unroll
                for (int j = 0; j < 6; ++j) xv[j] = s_in[ci][rr][px_base + j];
                #pragma unroll
                for (int i = 0; i < 4; ++i)
                    #pragma unroll
                    for (int j = 0; j < 4; ++j)
                        #pragma unroll
                        for (int kx = 0; kx < 3; ++kx)
                            acc[i][j] = fmaf(wv[i][rr * 3 + kx], xv[j + kx], acc[i][j]);
            }
        }
        __syncthreads();
    }

    #pragma unroll
    for (int i = 0; i < 4; ++i) {
        int co = co0 + co_base + i;
        if (co < Cout) {
            float* op = out + (long)b * out_bstride + (long)co * kHW + yRow * kW + x0 + px_base;
            #pragma unroll
            for (int j = 0; j < 4; ++j) op[j] = acc[i][j];
        }
    }
}

// ---------------------------------------------------------------------------
// BN statistics: one workgroup per channel, reduce over B*HW.
// ---------------------------------------------------------------------------
__global__ __launch_bounds__(256) void bn_stats(
    const float* __restrict__ y, float* __restrict__ mu, float* __restrict__ rs,
    long bstride)
{
    const int c   = blockIdx.x;
    const int tid = threadIdx.x;
    float s = 0.f, s2 = 0.f;
    for (int b = 0; b < kB; ++b) {
        const float* yb = y + (long)b * bstride + (long)c * kHW;
        for (int i = tid; i < kHW; i += 256) {
            float v = yb[i];
            s += v;
            s2 = fmaf(v, v, s2);
        }
    }
    #pragma unroll
    for (int off = 32; off >= 1; off >>= 1) {
        s  += __shfl_down(s, off);
        s2 += __shfl_down(s2, off);
    }
    __shared__ float ps[4][2];
    int wid = tid >> 6;
    if ((tid & 63) == 0) { ps[wid][0] = s; ps[wid][1] = s2; }
    __syncthreads();
    if (tid == 0) {
        float S  = ps[0][0] + ps[1][0] + ps[2][0] + ps[3][0];
        float S2 = ps[0][1] + ps[1][1] + ps[2][1] + ps[3][1];
        const float invN = 1.0f / (kB * kHW);
        float m   = S * invN;
        float var = S2 * invN - m * m;
        mu[c] = m;
        rs[c] = rsqrtf(var + 1e-5f);
    }
}

// ---------------------------------------------------------------------------
// BN normalize + ReLU (in place), channel-strided layout support.
// ---------------------------------------------------------------------------
__global__ __launch_bounds__(256) void bn_norm(
    float* __restrict__ y, const float* __restrict__ mu, const float* __restrict__ rs,
    const float* __restrict__ g, const float* __restrict__ bia, int C, long bstride)
{
    long total  = (long)kB * C * kHW;
    long stride = (long)gridDim.x * blockDim.x;
    for (long idx = (long)blockIdx.x * blockDim.x + threadIdx.x; idx < total; idx += stride) {
        long b   = idx / ((long)C * kHW);
        long rem = idx - b * (long)C * kHW;
        int  c   = (int)(rem / kHW);
        long p   = rem - (long)c * kHW;
        float* ptr = y + b * bstride + (long)c * kHW + p;
        float v = (*ptr - mu[c]) * rs[c] * g[c] + bia[c];
        *ptr = fmaxf(v, 0.f);
    }
}

// ---------------------------------------------------------------------------
// Fill pixel_f channels 15..17 <- x, 18..19 <- coords.
// ---------------------------------------------------------------------------
__global__ __launch_bounds__(256) void fill_extra(
    const float* __restrict__ x, const float* __restrict__ coords, float* __restrict__ pf)
{
    long idx = (long)blockIdx.x * 256 + threadIdx.x;   // B*5*HW
    if (idx >= (long)kB * 5 * kHW) return;
    int b   = (int)(idx / (5 * kHW));
    long rem = idx - (long)b * 5 * kHW;
    int c   = (int)(rem / kHW);
    long p  = rem - (long)c * kHW;
    float v = (c < 3) ? x[((long)b * 3 + c) * kHW + p]
                      : coords[((long)b * 2 + (c - 3)) * kHW + p];
    pf[((long)b * kC + 15 + c) * kHW + p] = v;
}

// ---------------------------------------------------------------------------
// cid output (as float; values 0..255 exact).
// ---------------------------------------------------------------------------
__global__ __launch_bounds__(256) void cid_kernel(float* __restrict__ out_cid)
{
    int idx = blockIdx.x * 256 + threadIdx.x;   // 9*HW
    if (idx >= 9 * kHW) return;
    int k = idx / kHW, p = idx - k * kHW;
    int r = p >> 8, c = p & 255;
    int rr = (r >> 4) + k / 3 - 1;
    int cc = (c >> 4) + k % 3 - 1;
    rr = rr < 0 ? 0 : (rr > 15 ? 15 : rr);
    cc = cc < 0 ? 0 : (cc > 15 ? 15 : cc);
    out_cid[idx] = (float)(rr * 16 + cc);
}

// ---------------------------------------------------------------------------
// Initial centroids: 16x16 block means of pixel_f.
// ---------------------------------------------------------------------------
__global__ __launch_bounds__(256) void cent_init(
    const float* __restrict__ pf, float* __restrict__ cent)
{
    int idx = blockIdx.x * 256 + threadIdx.x;   // B*20*256
    if (idx >= kB * kC * kNSPIX) return;
    int b   = idx / (kC * kNSPIX);
    int rem = idx - b * kC * kNSPIX;
    int c   = rem / kNSPIX;
    int s   = rem - c * kNSPIX;
    int sr = s >> 4, sc = s & 15;
    const float* base = pf + ((long)b * kC + c) * kHW;
    float sum = 0.f;
    for (int ry = 0; ry < 16; ++ry)
        for (int rx = 0; rx < 16; ++rx)
            sum += base[(sr * 16 + ry) * kW + sc * 16 + rx];
    cent[idx] = sum * (1.0f / 256.0f);
}

// ---------------------------------------------------------------------------
// Per-pixel 9-candidate distance + softmax -> aff (0 for invalid).
// ---------------------------------------------------------------------------
__global__ __launch_bounds__(256) void ssn_softmax(
    const float* __restrict__ pf, const float* __restrict__ cent, float* __restrict__ aff)
{
    __shared__ float s_cent[kC][kNSPIX];
    const int b   = blockIdx.y;
    const int tid = threadIdx.x;
    const float* cb = cent + (long)b * kC * kNSPIX;
    for (int i = tid; i < kC * kNSPIX; i += 256)
        s_cent[i >> 8][i & 255] = cb[i];
    __syncthreads();

    const int p  = blockIdx.x * 256 + tid;
    const int r  = p >> 8, c = p & 255;
    const int r0 = r >> 4, c0 = c >> 4;

    float f[kC];
    const float* pb = pf + (long)b * kC * kHW + p;
    #pragma unroll
    for (int ch = 0; ch < kC; ++ch) f[ch] = pb[(long)ch * kHW];

    float dist[9];
    bool  val[9];
    float mx = -1e30f;
    #pragma unroll
    for (int k = 0; k < 9; ++k) {
        int rr = r0 + k / 3 - 1;
        int cc = c0 + k % 3 - 1;
        bool v = (rr >= 0 && rr < 16 && cc >= 0 && cc < 16);
        val[k] = v;
        int sid = v ? rr * 16 + cc : 0;
        float d = 0.f;
        #pragma unroll
        for (int ch = 0; ch < kC; ++ch) {
            float t = f[ch] - s_cent[ch][sid];
            d = fmaf(t, t, d);
        }
        dist[k] = d;
        if (v) mx = fmaxf(mx, -d);
    }
    float e[9], sum = 0.f;
    #pragma unroll
    for (int k = 0; k < 9; ++k) {
        e[k] = val[k] ? expf(-dist[k] - mx) : 0.f;
        sum += e[k];
    }
    float inv = 1.0f / sum;
    float* ab = aff + (long)b * 9 * kHW + p;
    #pragma unroll
    for (int k = 0; k < 9; ++k) ab[(long)k * kHW] = e[k] * inv;
}

// ---------------------------------------------------------------------------
// Centroid update: one workgroup per (b, superpixel). Gather formulation:
// superpixel (sr,sc) receives pixels of block (br,bc)=(sr-dr,sc-dc) at
// candidate k=(dr+1)*3+(dc+1). No atomics.
// ---------------------------------------------------------------------------
__global__ __launch_bounds__(256) void ssn_update(
    const float* __restrict__ pf, const float* __restrict__ aff, float* __restrict__ cent)
{
    const int b  = blockIdx.y;
    const int s  = blockIdx.x;
    const int sr = s >> 4, sc = s & 15;
    const int tid = threadIdx.x;
    const int ty = tid >> 4, tx = tid & 15;

    float acc[kC + 1];
    #pragma unroll
    for (int i = 0; i <= kC; ++i) acc[i] = 0.f;

    #pragma unroll
    for (int k = 0; k < 9; ++k) {
        int dr = k / 3 - 1, dc = k % 3 - 1;
        int br = sr - dr, bc = sc - dc;
        if (br < 0 || br > 15 || bc < 0 || bc > 15) continue;
        int p = (br * 16 + ty) * kW + bc * 16 + tx;
        float w = aff[((long)b * 9 + k) * kHW + p];
        const float* pb = pf + (long)b * kC * kHW + p;
        acc[kC] += w;
        #pragma unroll
        for (int ch = 0; ch < kC; ++ch)
            acc[ch] = fmaf(w, pb[(long)ch * kHW], acc[ch]);
    }

    #pragma unroll
    for (int off = 32; off >= 1; off >>= 1)
        #pragma unroll
        for (int ch = 0; ch <= kC; ++ch)
            acc[ch] += __shfl_down(acc[ch], off);

    __shared__ float part[4][kC + 1];
    int wid = tid >> 6;
    if ((tid & 63) == 0)
        #pragma unroll
        for (int ch = 0; ch <= kC; ++ch) part[wid][ch] = acc[ch];
    __syncthreads();
    if (tid < kC) {
        float num = part[0][tid] + part[1][tid] + part[2][tid] + part[3][tid];
        float den = part[0][kC] + part[1][kC] + part[2][kC] + part[3][kC];
        cent[((long)b * kC + tid) * kNSPIX + s] = num / (den + 1e-16f);
    }
}

// ---------------------------------------------------------------------------
extern "C" void kernel_launch(void* const* d_in, const int* in_sizes, int n_in,
                              void* d_out, int out_size, void* d_ws, size_t ws_size,
                              hipStream_t stream)
{
    const float* x      = (const float*)d_in[0];
    const float* coords = (const float*)d_in[1];
    const float* feats  = (const float*)d_in[2];
    const float* W1 = (const float*)d_in[3];
    const float* g1 = (const float*)d_in[4];
    const float* b1 = (const float*)d_in[5];
    const float* W2 = (const float*)d_in[6];
    const float* g2 = (const float*)d_in[7];
    const float* b2 = (const float*)d_in[8];
    const float* W3 = (const float*)d_in[9];
    const float* g3 = (const float*)d_in[10];
    const float* b3 = (const float*)d_in[11];

    // workspace layout (floats)
    float* ws   = (float*)d_ws;
    float* y1   = ws;                                   // 2*500*65536
    float* y2   = y1 + (long)kB * 500 * kHW;            // 2*100*65536
    float* pf   = y2 + (long)kB * 100 * kHW;            // 2*20*65536
    float* mu   = pf + (long)kB * kC * kHW;             // 512
    float* rs   = mu + 512;                             // 512

    // output layout (floats)
    float* aff_out  = (float*)d_out;                    // B*9*HW
    float* cid_out  = aff_out + (long)kB * 9 * kHW;     // 9*HW
    float* cent_out = cid_out + (long)9 * kHW;          // B*20*256

    // ---- conv1: 1029 -> 500 ----
    conv3x3<<<dim3(1024, 8, kB), 256, 0, stream>>>(
        feats, W1, y1, 1029, 500, (long)1029 * kHW, (long)500 * kHW);
    bn_stats<<<500, 256, 0, stream>>>(y1, mu, rs, (long)500 * kHW);
    bn_norm<<<8192, 256, 0, stream>>>(y1, mu, rs, g1, b1, 500, (long)500 * kHW);

    // ---- conv2: 500 -> 100 ----
    conv3x3<<<dim3(1024, 2, kB), 256, 0, stream>>>(
        y1, W2, y2, 500, 100, (long)500 * kHW, (long)100 * kHW);
    bn_stats<<<100, 256, 0, stream>>>(y2, mu, rs, (long)100 * kHW);
    bn_norm<<<2048, 256, 0, stream>>>(y2, mu, rs, g2, b2, 100, (long)100 * kHW);

    // ---- conv3: 100 -> 15, writes into pf channels 0..14 ----
    conv3x3<<<dim3(1024, 1, kB), 256, 0, stream>>>(
        y2, W3, pf, 100, 15, (long)100 * kHW, (long)kC * kHW);
    bn_stats<<<15, 256, 0, stream>>>(pf, mu, rs, (long)kC * kHW);
    bn_norm<<<512, 256, 0, stream>>>(pf, mu, rs, g3, b3, 15, (long)kC * kHW);

    // ---- concat x, coords into pf channels 15..19 ----
    fill_extra<<<(kB * 5 * kHW + 255) / 256, 256, 0, stream>>>(x, coords, pf);

    // ---- cid output ----
    cid_kernel<<<(9 * kHW + 255) / 256, 256, 0, stream>>>(cid_out);

    // ---- initial centroids ----
    cent_init<<<(kB * kC * kNSPIX + 255) / 256, 256, 0, stream>>>(pf, cent_out);

    // ---- SSN iterations ----
    for (int it = 0; it < kNITER; ++it) {
        ssn_softmax<<<dim3(kHW / 256, kB), 256, 0, stream>>>(pf, cent_out, aff_out);
        ssn_update<<<dim3(kNSPIX, kB), 256, 0, stream>>>(pf, aff_out, cent_out);
    }
}

// Round 2
// 5884.635 us; speedup vs baseline: 5.6873x; 5.6873x over previous
//
#include <hip/hip_runtime.h>
#include <math.h>

#define kB 2
#define kH 256
#define kW 256
#define kHW 65536
#define kNSPIX 256
#define kC 20
#define kNITER 10

typedef unsigned int uint;
typedef unsigned short ushort;

using f32x4  = __attribute__((ext_vector_type(4))) float;
using bf16x8 = __attribute__((ext_vector_type(8))) __bf16;

__device__ __forceinline__ ushort f2bf(float f) {
    uint u = __float_as_uint(f);
    u = (u + 0x7FFFu + ((u >> 16) & 1u)) >> 16;
    return (ushort)u;
}
__device__ __forceinline__ float bf2f(uint h) {
    return __uint_as_float(h << 16);
}

// ---------------------------------------------------------------------------
// feats fp32 NCHW -> bf16 NHWC (ci contiguous), zero-padded to Cin_pad.
// grid: (Cin_pad/32, HW/64, B)
// ---------------------------------------------------------------------------
__global__ __launch_bounds__(256) void xtrans(
    const float* __restrict__ src, ushort* __restrict__ dst,
    int Cin_real, int Cin_pad)
{
    __shared__ float s[64][33];
    const int ci0 = blockIdx.x * 32;
    const int p0  = blockIdx.y * 64;
    const int b   = blockIdx.z;
    const int tid = threadIdx.x;
    for (int e = tid; e < 2048; e += 256) {
        int ci = e >> 6, px = e & 63;
        int cig = ci0 + ci;
        float v = 0.f;
        if (cig < Cin_real) v = src[((long)b * Cin_real + cig) * kHW + p0 + px];
        s[px][ci] = v;
    }
    __syncthreads();
    const int px = tid >> 2, g = tid & 3;
    uint4 o;
    o.x = (uint)f2bf(s[px][g*8+0]) | ((uint)f2bf(s[px][g*8+1]) << 16);
    o.y = (uint)f2bf(s[px][g*8+2]) | ((uint)f2bf(s[px][g*8+3]) << 16);
    o.z = (uint)f2bf(s[px][g*8+4]) | ((uint)f2bf(s[px][g*8+5]) << 16);
    o.w = (uint)f2bf(s[px][g*8+6]) | ((uint)f2bf(s[px][g*8+7]) << 16);
    *(uint4*)(dst + ((long)(b * kHW + p0 + px)) * Cin_pad + ci0 + g * 8) = o;
}

// ---------------------------------------------------------------------------
// W fp32 [co][ci][tap] -> bf16 Wt[tap][co_pad][ci_pad], zero-padded.
// ---------------------------------------------------------------------------
__global__ __launch_bounds__(256) void wtrans(
    const float* __restrict__ W, ushort* __restrict__ Wt,
    int Cout_real, int Cin_real, int Cout_pad, int Cin_pad)
{
    long idx = (long)blockIdx.x * 256 + threadIdx.x;
    long total = (long)9 * Cout_pad * Cin_pad;
    if (idx >= total) return;
    int t   = (int)(idx / ((long)Cout_pad * Cin_pad));
    long r  = idx - (long)t * Cout_pad * Cin_pad;
    int co  = (int)(r / Cin_pad);
    int ci  = (int)(r - (long)co * Cin_pad);
    float v = 0.f;
    if (co < Cout_real && ci < Cin_real) v = W[((long)co * Cin_real + ci) * 9 + t];
    Wt[idx] = f2bf(v);
}

// ---------------------------------------------------------------------------
// Implicit-GEMM conv3x3 SAME, bf16 MFMA 16x16x32, NHWC.
// Block: 64 cout x 128 px (one row segment). 4 waves, wave = 32co x 64px.
// K-loop: ci chunks of 32, 9 taps accumulated per chunk.
// Epilogue: NHWC bf16 store + per-channel (sum, sumsq) atomics for BN.
// grid: (Cout_pad/64, 512, B)
// ---------------------------------------------------------------------------
__global__ __launch_bounds__(256, 2) void conv_mfma(
    const ushort* __restrict__ Xt, const ushort* __restrict__ Wt,
    ushort* __restrict__ Yt, float* __restrict__ stats,
    int Cin_pad, int Cout_pad)
{
    __shared__ __align__(16) ushort As[9 * 64 * 32];   // [tap][co][ci-swizzled]
    __shared__ __align__(16) ushort Bs[3 * 130 * 32];  // [row][px][ci-swizzled]

    const int tid  = threadIdx.x;
    const int lane = tid & 63;
    const int wave = tid >> 6;
    const int l15  = lane & 15;
    const int quad = lane >> 4;
    const int co_w = (wave >> 1) * 32;
    const int px_w = (wave & 1) * 64;
    const int co0  = blockIdx.x * 64;
    const int py   = blockIdx.y >> 1;
    const int x0   = (blockIdx.y & 1) * 128;
    const int b    = blockIdx.z;

    f32x4 acc[2][4];
    #pragma unroll
    for (int i = 0; i < 2; ++i)
        #pragma unroll
        for (int j = 0; j < 4; ++j) acc[i][j] = (f32x4)0.0f;

    for (int ci0 = 0; ci0 < Cin_pad; ci0 += 32) {
        // ---- stage B: 3 rows x 130 px x 32 ci ----
        for (int u = tid; u < 1560; u += 256) {
            int r   = u / 520;
            int rem = u - r * 520;
            int pxs = rem >> 2;
            int g   = rem & 3;
            int ys  = py + r - 1;
            int xs  = x0 + pxs - 1;
            uint4 v = {0u, 0u, 0u, 0u};
            if ((unsigned)ys < kH && (unsigned)xs < kW)
                v = *(const uint4*)(Xt + ((long)(b * kHW + ys * kW + xs)) * Cin_pad + ci0 + g * 8);
            *(uint4*)(Bs + (r * 130 + pxs) * 32 + ((g ^ (pxs & 3)) * 8)) = v;
        }
        // ---- stage A: 9 taps x 64 co x 32 ci ----
        for (int u = tid; u < 2304; u += 256) {
            int t   = u >> 8;
            int rem = u & 255;
            int co  = rem >> 2;
            int g   = rem & 3;
            uint4 v = *(const uint4*)(Wt + ((long)t * Cout_pad + co0 + co) * Cin_pad + ci0 + g * 8);
            *(uint4*)(As + (t * 64 + co) * 32 + ((g ^ (co & 3)) * 8)) = v;
        }
        __syncthreads();

        #pragma unroll
        for (int t = 0; t < 9; ++t) {
            const int ky = t / 3, kx = t % 3;
            bf16x8 a0 = *(const bf16x8*)(As + (t * 64 + co_w + l15)      * 32 + ((quad ^ (l15 & 3)) * 8));
            bf16x8 a1 = *(const bf16x8*)(As + (t * 64 + co_w + 16 + l15) * 32 + ((quad ^ (l15 & 3)) * 8));
            #pragma unroll
            for (int j = 0; j < 4; ++j) {
                int pxs = px_w + j * 16 + l15 + kx;
                bf16x8 bb = *(const bf16x8*)(Bs + (ky * 130 + pxs) * 32 + ((quad ^ (pxs & 3)) * 8));
                acc[0][j] = __builtin_amdgcn_mfma_f32_16x16x32_bf16(a0, bb, acc[0][j], 0, 0, 0);
                acc[1][j] = __builtin_amdgcn_mfma_f32_16x16x32_bf16(a1, bb, acc[1][j], 0, 0, 0);
            }
        }
        __syncthreads();
    }

    // ---- epilogue: store NHWC bf16 + BN stats ----
    const long pxbase = (long)(b * kHW + py * kW + x0 + px_w);
    #pragma unroll
    for (int i = 0; i < 2; ++i) {
        #pragma unroll
        for (int reg = 0; reg < 4; ++reg) {
            int co_r = co0 + co_w + i * 16 + quad * 4 + reg;
            float s = 0.f, s2 = 0.f;
            #pragma unroll
            for (int j = 0; j < 4; ++j) {
                float v = acc[i][j][reg];
                s += v;
                s2 = fmaf(v, v, s2);
                Yt[(pxbase + j * 16 + l15) * Cout_pad + co_r] = f2bf(v);
            }
            #pragma unroll
            for (int off = 1; off <= 8; off <<= 1) {
                s  += __shfl_xor(s, off);
                s2 += __shfl_xor(s2, off);
            }
            if (l15 == 0) {
                atomicAdd(&stats[co_r], s);
                atomicAdd(&stats[Cout_pad + co_r], s2);
            }
        }
    }
}

// ---------------------------------------------------------------------------
__global__ void finalize_stats(const float* __restrict__ stats,
                               float* __restrict__ murs, int Cout_pad)
{
    int c = blockIdx.x * 256 + threadIdx.x;
    if (c >= Cout_pad) return;
    const float invN = 1.0f / (float)(kB * kHW);
    float mu  = stats[c] * invN;
    float var = stats[Cout_pad + c] * invN - mu * mu;
    murs[c] = mu;
    murs[Cout_pad + c] = rsqrtf(var + 1e-5f);
}

// ---------------------------------------------------------------------------
// BN + ReLU in place on NHWC bf16; pad channels forced to 0.
// ---------------------------------------------------------------------------
__global__ __launch_bounds__(256) void bn_relu_nhwc(
    ushort* __restrict__ Y, const float* __restrict__ murs,
    const float* __restrict__ g, const float* __restrict__ bia,
    int C_real, int C_pad)
{
    long idx = (long)blockIdx.x * 256 + threadIdx.x;
    long total = (long)kB * kHW * (C_pad / 8);
    if (idx >= total) return;
    int cg = (int)(idx % (C_pad / 8));
    long p = idx / (C_pad / 8);
    ushort* ptr = Y + p * C_pad + (long)cg * 8;
    uint4 v = *(uint4*)ptr;
    uint w[4] = {v.x, v.y, v.z, v.w};
    uint o[4];
    #pragma unroll
    for (int q = 0; q < 4; ++q) {
        int c0 = cg * 8 + q * 2;
        int c1 = c0 + 1;
        float f0 = 0.f, f1 = 0.f;
        if (c0 < C_real)
            f0 = fmaxf((bf2f(w[q] & 0xFFFFu) - murs[c0]) * murs[C_pad + c0] * g[c0] + bia[c0], 0.f);
        if (c1 < C_real)
            f1 = fmaxf((bf2f(w[q] >> 16) - murs[c1]) * murs[C_pad + c1] * g[c1] + bia[c1], 0.f);
        o[q] = (uint)f2bf(f0) | ((uint)f2bf(f1) << 16);
    }
    uint4 ov = {o[0], o[1], o[2], o[3]};
    *(uint4*)ptr = ov;
}

// ---------------------------------------------------------------------------
// conv3 output (NHWC bf16, C_pad=64) -> BN+ReLU -> pf planar fp32 ch 0..14
// ---------------------------------------------------------------------------
__global__ __launch_bounds__(256) void bn_to_pf(
    const ushort* __restrict__ y3, const float* __restrict__ murs,
    const float* __restrict__ g, const float* __restrict__ bia,
    float* __restrict__ pf)
{
    long idx = (long)blockIdx.x * 256 + threadIdx.x;
    if (idx >= (long)kB * 15 * kHW) return;
    int b  = (int)(idx / (15 * kHW));
    long r = idx - (long)b * 15 * kHW;
    int ch = (int)(r / kHW);
    long p = r - (long)ch * kHW;
    float v = bf2f((uint)y3[((long)b * kHW + p) * 64 + ch]);
    v = fmaxf((v - murs[ch]) * murs[64 + ch] * g[ch] + bia[ch], 0.f);
    pf[((long)b * kC + ch) * kHW + p] = v;
}

// ---------------------------------------------------------------------------
__global__ __launch_bounds__(256) void fill_extra(
    const float* __restrict__ x, const float* __restrict__ coords, float* __restrict__ pf)
{
    long idx = (long)blockIdx.x * 256 + threadIdx.x;
    if (idx >= (long)kB * 5 * kHW) return;
    int b   = (int)(idx / (5 * kHW));
    long rem = idx - (long)b * 5 * kHW;
    int c   = (int)(rem / kHW);
    long p  = rem - (long)c * kHW;
    float v = (c < 3) ? x[((long)b * 3 + c) * kHW + p]
                      : coords[((long)b * 2 + (c - 3)) * kHW + p];
    pf[((long)b * kC + 15 + c) * kHW + p] = v;
}

// ---------------------------------------------------------------------------
__global__ __launch_bounds__(256) void cid_kernel(float* __restrict__ out_cid)
{
    int idx = blockIdx.x * 256 + threadIdx.x;
    if (idx >= 9 * kHW) return;
    int k = idx / kHW, p = idx - k * kHW;
    int r = p >> 8, c = p & 255;
    int rr = (r >> 4) + k / 3 - 1;
    int cc = (c >> 4) + k % 3 - 1;
    rr = rr < 0 ? 0 : (rr > 15 ? 15 : rr);
    cc = cc < 0 ? 0 : (cc > 15 ? 15 : cc);
    out_cid[idx] = (float)(rr * 16 + cc);
}

// ---------------------------------------------------------------------------
__global__ __launch_bounds__(256) void cent_init(
    const float* __restrict__ pf, float* __restrict__ cent)
{
    int idx = blockIdx.x * 256 + threadIdx.x;
    if (idx >= kB * kC * kNSPIX) return;
    int b   = idx / (kC * kNSPIX);
    int rem = idx - b * (kC * kNSPIX);
    int c   = rem / kNSPIX;
    int s   = rem - c * kNSPIX;
    int sr = s >> 4, sc = s & 15;
    const float* base = pf + ((long)b * kC + c) * kHW;
    float sum = 0.f;
    for (int ry = 0; ry < 16; ++ry)
        for (int rx = 0; rx < 16; ++rx)
            sum += base[(sr * 16 + ry) * kW + sc * 16 + rx];
    cent[idx] = sum * (1.0f / 256.0f);
}

// ---------------------------------------------------------------------------
__global__ __launch_bounds__(256) void ssn_softmax(
    const float* __restrict__ pf, const float* __restrict__ cent, float* __restrict__ aff)
{
    __shared__ float s_cent[kC][kNSPIX];
    const int b   = blockIdx.y;
    const int tid = threadIdx.x;
    const float* cb = cent + (long)b * kC * kNSPIX;
    for (int i = tid; i < kC * kNSPIX; i += 256)
        s_cent[i >> 8][i & 255] = cb[i];
    __syncthreads();

    const int p  = blockIdx.x * 256 + tid;
    const int r  = p >> 8, c = p & 255;
    const int r0 = r >> 4, c0 = c >> 4;

    float f[kC];
    const float* pb = pf + (long)b * kC * kHW + p;
    #pragma unroll
    for (int ch = 0; ch < kC; ++ch) f[ch] = pb[(long)ch * kHW];

    float dist[9];
    bool  val[9];
    float mx = -1e30f;
    #pragma unroll
    for (int k = 0; k < 9; ++k) {
        int rr = r0 + k / 3 - 1;
        int cc = c0 + k % 3 - 1;
        bool v = (rr >= 0 && rr < 16 && cc >= 0 && cc < 16);
        val[k] = v;
        int sid = v ? rr * 16 + cc : 0;
        float d = 0.f;
        #pragma unroll
        for (int ch = 0; ch < kC; ++ch) {
            float t = f[ch] - s_cent[ch][sid];
            d = fmaf(t, t, d);
        }
        dist[k] = d;
        if (v) mx = fmaxf(mx, -d);
    }
    float e[9], sum = 0.f;
    #pragma unroll
    for (int k = 0; k < 9; ++k) {
        e[k] = val[k] ? expf(-dist[k] - mx) : 0.f;
        sum += e[k];
    }
    float inv = 1.0f / sum;
    float* ab = aff + (long)b * 9 * kHW + p;
    #pragma unroll
    for (int k = 0; k < 9; ++k) ab[(long)k * kHW] = e[k] * inv;
}

// ---------------------------------------------------------------------------
__global__ __launch_bounds__(256) void ssn_update(
    const float* __restrict__ pf, const float* __restrict__ aff, float* __restrict__ cent)
{
    const int b  = blockIdx.y;
    const int s  = blockIdx.x;
    const int sr = s >> 4, sc = s & 15;
    const int tid = threadIdx.x;
    const int ty = tid >> 4, tx = tid & 15;

    float acc[kC + 1];
    #pragma unroll
    for (int i = 0; i <= kC; ++i) acc[i] = 0.f;

    #pragma unroll
    for (int k = 0; k < 9; ++k) {
        int dr = k / 3 - 1, dc = k % 3 - 1;
        int br = sr - dr, bc = sc - dc;
        if (br < 0 || br > 15 || bc < 0 || bc > 15) continue;
        int p = (br * 16 + ty) * kW + bc * 16 + tx;
        float w = aff[((long)b * 9 + k) * kHW + p];
        const float* pb = pf + (long)b * kC * kHW + p;
        acc[kC] += w;
        #pragma unroll
        for (int ch = 0; ch < kC; ++ch)
            acc[ch] = fmaf(w, pb[(long)ch * kHW], acc[ch]);
    }

    #pragma unroll
    for (int off = 32; off >= 1; off >>= 1)
        #pragma unroll
        for (int ch = 0; ch <= kC; ++ch)
            acc[ch] += __shfl_down(acc[ch], off);

    __shared__ float part[4][kC + 1];
    int wid = tid >> 6;
    if ((tid & 63) == 0)
        #pragma unroll
        for (int ch = 0; ch <= kC; ++ch) part[wid][ch] = acc[ch];
    __syncthreads();
    if (tid < kC) {
        float num = part[0][tid] + part[1][tid] + part[2][tid] + part[3][tid];
        float den = part[0][kC] + part[1][kC] + part[2][kC] + part[3][kC];
        cent[((long)b * kC + tid) * kNSPIX + s] = num / (den + 1e-16f);
    }
}

// ---------------------------------------------------------------------------
extern "C" void kernel_launch(void* const* d_in, const int* in_sizes, int n_in,
                              void* d_out, int out_size, void* d_ws, size_t ws_size,
                              hipStream_t stream)
{
    const float* x      = (const float*)d_in[0];
    const float* coords = (const float*)d_in[1];
    const float* feats  = (const float*)d_in[2];
    const float* W1 = (const float*)d_in[3];
    const float* g1 = (const float*)d_in[4];
    const float* b1 = (const float*)d_in[5];
    const float* W2 = (const float*)d_in[6];
    const float* g2 = (const float*)d_in[7];
    const float* b2 = (const float*)d_in[8];
    const float* W3 = (const float*)d_in[9];
    const float* g3 = (const float*)d_in[10];
    const float* b3 = (const float*)d_in[11];

    // ---- workspace layout (bytes) ----
    char* ws = (char*)d_ws;
    ushort* Xt1 = (ushort*)ws;                         // 2*65536*1056
    ws += (long)2 * kHW * 1056 * 2;
    ushort* Wt1 = (ushort*)ws;  ws += (long)9 * 512 * 1056 * 2;
    ushort* y1t = (ushort*)ws;  ws += (long)2 * kHW * 512 * 2;
    ushort* Wt2 = (ushort*)ws;  ws += (long)9 * 128 * 512 * 2;
    ushort* y2t = (ushort*)ws;  ws += (long)2 * kHW * 128 * 2;
    ushort* Wt3 = (ushort*)ws;  ws += (long)9 * 64 * 128 * 2;
    ushort* y3t = (ushort*)ws;  ws += (long)2 * kHW * 64 * 2;
    float*  pf  = (float*)ws;   ws += (long)2 * kC * kHW * 4;
    float* stats1 = (float*)ws; ws += 1024 * 4;
    float* stats2 = (float*)ws; ws += 256 * 4;
    float* stats3 = (float*)ws; ws += 128 * 4;
    float* murs1  = (float*)ws; ws += 1024 * 4;
    float* murs2  = (float*)ws; ws += 256 * 4;
    float* murs3  = (float*)ws; ws += 128 * 4;

    hipMemsetAsync(stats1, 0, (1024 + 256 + 128 + 1024 + 256 + 128) * 4, stream);

    // ---- output layout ----
    float* aff_out  = (float*)d_out;
    float* cid_out  = aff_out + (long)kB * 9 * kHW;
    float* cent_out = cid_out + (long)9 * kHW;

    // ---- pre-passes ----
    xtrans<<<dim3(33, 1024, kB), 256, 0, stream>>>(feats, Xt1, 1029, 1056);
    wtrans<<<(int)(((long)9 * 512 * 1056 + 255) / 256), 256, 0, stream>>>(W1, Wt1, 500, 1029, 512, 1056);
    wtrans<<<(int)(((long)9 * 128 * 512 + 255) / 256), 256, 0, stream>>>(W2, Wt2, 100, 500, 128, 512);
    wtrans<<<(int)(((long)9 * 64 * 128 + 255) / 256), 256, 0, stream>>>(W3, Wt3, 15, 100, 64, 128);

    // ---- conv1: 1029 -> 500 ----
    conv_mfma<<<dim3(8, 512, kB), 256, 0, stream>>>(Xt1, Wt1, y1t, stats1, 1056, 512);
    finalize_stats<<<2, 256, 0, stream>>>(stats1, murs1, 512);
    bn_relu_nhwc<<<(int)(((long)kB * kHW * 64 + 255) / 256), 256, 0, stream>>>(y1t, murs1, g1, b1, 500, 512);

    // ---- conv2: 500 -> 100 ----
    conv_mfma<<<dim3(2, 512, kB), 256, 0, stream>>>(y1t, Wt2, y2t, stats2, 512, 128);
    finalize_stats<<<1, 256, 0, stream>>>(stats2, murs2, 128);
    bn_relu_nhwc<<<(int)(((long)kB * kHW * 16 + 255) / 256), 256, 0, stream>>>(y2t, murs2, g2, b2, 100, 128);

    // ---- conv3: 100 -> 15 ----
    conv_mfma<<<dim3(1, 512, kB), 256, 0, stream>>>(y2t, Wt3, y3t, stats3, 128, 64);
    finalize_stats<<<1, 256, 0, stream>>>(stats3, murs3, 64);
    bn_to_pf<<<(int)(((long)kB * 15 * kHW + 255) / 256), 256, 0, stream>>>(y3t, murs3, g3, b3, pf);

    // ---- pf extra channels, cid, centroids ----
    fill_extra<<<(int)(((long)kB * 5 * kHW + 255) / 256), 256, 0, stream>>>(x, coords, pf);
    cid_kernel<<<(9 * kHW + 255) / 256, 256, 0, stream>>>(cid_out);
    cent_init<<<(kB * kC * kNSPIX + 255) / 256, 256, 0, stream>>>(pf, cent_out);

    // ---- SSN iterations ----
    for (int it = 0; it < kNITER; ++it) {
        ssn_softmax<<<dim3(kHW / 256, kB), 256, 0, stream>>>(pf, cent_out, aff_out);
        ssn_update<<<dim3(kNSPIX, kB), 256, 0, stream>>>(pf, aff_out, cent_out);
    }
}